// Round 8
// baseline (497.570 us; speedup 1.0000x reference)
//
#include <hip/hip_runtime.h>
#include <hip/hip_bf16.h>

// Problem constants: B,T,V,E,U = 256,512,20000,128,128
#define BB 256
#define TT 512
#define VV 20000
#define EE 128
#define UU 128
#define G4 512   // 4*U gate width
#define ROWS 2   // batch rows per block

typedef _Float16 f16x8 __attribute__((ext_vector_type(8)));
typedef float    f32x4 __attribute__((ext_vector_type(4)));

__device__ __forceinline__ float sigmoid_f(float x) {
    float e = __expf(-x);
    return __builtin_amdgcn_rcpf(1.0f + e);
}
__device__ __forceinline__ float tanh_f(float x) {
    float e = __expf(2.0f * x);
    return 1.0f - 2.0f * __builtin_amdgcn_rcpf(e + 1.0f);
}

// ---------------------------------------------------------------------------
// Phase 1: projected-token table in GATE-MINOR layout:
//   P2[v][u][g] = sum_e emb[v][e]*K[e][g*128+u] + bias[g*128+u]
// ---------------------------------------------------------------------------
__global__ __launch_bounds__(512, 2) void proj_kernel(
    const float* __restrict__ emb, const float* __restrict__ wk,
    const float* __restrict__ bias, float* __restrict__ P2) {
    const int tid = threadIdx.x;
    const int g   = tid & 3;
    const int u   = tid >> 2;
    const int col = g * 128 + u;
    const int v0  = blockIdx.x * 16;

    __shared__ float elds[16 * EE];
    ((float4*)elds)[tid] = ((const float4*)(emb + (size_t)v0 * EE))[tid];
    __syncthreads();

    float bcol = bias[col];
    float acc[16];
#pragma unroll
    for (int r = 0; r < 16; ++r) acc[r] = bcol;

    const float4* elds4 = (const float4*)elds;
    for (int e0 = 0; e0 < EE; e0 += 4) {
        float k0 = wk[(e0 + 0) * G4 + col];
        float k1 = wk[(e0 + 1) * G4 + col];
        float k2 = wk[(e0 + 2) * G4 + col];
        float k3 = wk[(e0 + 3) * G4 + col];
#pragma unroll
        for (int r = 0; r < 16; ++r) {
            float4 ev = elds4[r * 32 + (e0 >> 2)];
            acc[r] = fmaf(ev.x, k0, acc[r]);
            acc[r] = fmaf(ev.y, k1, acc[r]);
            acc[r] = fmaf(ev.z, k2, acc[r]);
            acc[r] = fmaf(ev.w, k3, acc[r]);
        }
    }
#pragma unroll
    for (int r = 0; r < 16; ++r)
        P2[(size_t)(v0 + r) * G4 + tid] = acc[r];   // [v][u][g], coalesced
}

// ---------------------------------------------------------------------------
// Phase 2: sequential LSTM via MFMA, TWO rows per block so row A's VALU
// phase overlaps row B's MFMA phase (pipes were strictly serial at 1 row).
// Weights (B-frags) shared across rows. Gate-specialized activations with a
// wave-private LDS exchange (gbuf segment per wave: same-wave ordering, no
// barrier). Scalar gate-minor P loads, depth-2 in-flight, issued early.
// Raw s_barrier + lgkmcnt(0)-only drain per step (P loads cross barriers).
// ---------------------------------------------------------------------------
__global__ __launch_bounds__(512, 1) void lstm_kernel(
    const int* __restrict__ tokens, const float* __restrict__ rk,
    const float* __restrict__ P2, const float* __restrict__ dense_w,
    const float* __restrict__ dense_b, float* __restrict__ out) {
    const int tid = threadIdx.x;
    const int w   = tid >> 6;       // wave 0..7
    const int l   = tid & 63;       // lane
    const int j   = l & 15;         // unit index within the wave's 16
    const int kq  = l >> 4;         // lane's gate (0=i,1=f,2=g,3=o)
    const int rb  = blockIdx.x * ROWS;
    const int ucol = 16 * w + j;    // unit column

    __shared__ __align__(16) _Float16 hbuf[ROWS][2][UU];
    __shared__ __align__(16) float    gbuf[ROWS][G4];   // wave-private segs
    __shared__ int tokLDS[ROWS][TT + 8];
    __shared__ float red[ROWS][8];

    // ---- B-fragments (shared by both rows): rk[32kt+8kq+i][g*128+ucol] ----
    f16x8 bf[4][4];
#pragma unroll
    for (int kt = 0; kt < 4; ++kt) {
#pragma unroll
        for (int g = 0; g < 4; ++g) {
            f16x8 v;
#pragma unroll
            for (int i = 0; i < 8; ++i) {
                v[i] = (_Float16)rk[(size_t)(32 * kt + 8 * kq + i) * G4
                                    + g * 128 + ucol];
            }
            bf[kt][g] = v;
        }
    }

#pragma unroll
    for (int r = 0; r < ROWS; ++r) {
        tokLDS[r][tid] = tokens[(size_t)(rb + r) * TT + tid];
        if (tid < 8) tokLDS[r][TT + tid] = tokens[(size_t)(rb + r) * TT + TT - 1];
    }
    if (tid < UU) { hbuf[0][0][tid] = (_Float16)0.f; hbuf[1][0][tid] = (_Float16)0.f; }

    const int pOff = ucol * 4 + kq;          // this lane's dword in a P2 row
    float c0 = 0.f, c1 = 0.f, hv0 = 0.f, hv1 = 0.f;

    const int* tr0 = tokens + (size_t)rb * TT;
    const int* tr1 = tokens + (size_t)(rb + 1) * TT;
    // depth-2 prologue (parity 0/1)
    float pA0 = P2[(size_t)tr0[0] * G4 + pOff];
    float pB0 = P2[(size_t)tr1[0] * G4 + pOff];
    float pA1 = P2[(size_t)tr0[1] * G4 + pOff];
    float pB1 = P2[(size_t)tr1[1] * G4 + pOff];
    __syncthreads();

    const f32x4 cz = {0.f, 0.f, 0.f, 0.f};

#define LSTM_STEP(PAR, PA, PB)                                                 \
    {                                                                          \
        const int ia = t + (PAR) + 2;                                          \
        int vA = tokLDS[0][ia];                                                \
        int vB = tokLDS[1][ia];                                                \
        float curA = (PA), curB = (PB);                                        \
        int sA = __builtin_amdgcn_readfirstlane(vA);                           \
        int sB = __builtin_amdgcn_readfirstlane(vB);                           \
        (PA) = P2[(size_t)sA * G4 + pOff];   /* in flight ~2 steps */          \
        (PB) = P2[(size_t)sB * G4 + pOff];                                     \
        f16x8 afA[4], afB[4];                                                  \
        _Pragma("unroll")                                                      \
        for (int kt = 0; kt < 4; ++kt) {                                       \
            afA[kt] = *(const f16x8*)&hbuf[0][PAR][32 * kt + 8 * kq];          \
            afB[kt] = *(const f16x8*)&hbuf[1][PAR][32 * kt + 8 * kq];          \
        }                                                                      \
        /* --- row A: 4 gate chains (16 MFMA) --- */                           \
        f32x4 accA[4];                                                         \
        _Pragma("unroll")                                                      \
        for (int g = 0; g < 4; ++g) {                                          \
            f32x4 a = __builtin_amdgcn_mfma_f32_16x16x32_f16(afA[0], bf[0][g], cz, 0, 0, 0); \
            a = __builtin_amdgcn_mfma_f32_16x16x32_f16(afA[1], bf[1][g], a, 0, 0, 0); \
            a = __builtin_amdgcn_mfma_f32_16x16x32_f16(afA[2], bf[2][g], a, 0, 0, 0); \
            a = __builtin_amdgcn_mfma_f32_16x16x32_f16(afA[3], bf[3][g], a, 0, 0, 0); \
            accA[g] = a;                                                       \
        }                                                                      \
        /* --- row A: own-gate activation (overlaps row B's MFMAs) --- */      \
        {                                                                      \
            float z0 = accA[0][0], z1 = accA[1][0], z2 = accA[2][0], z3 = accA[3][0]; \
            float zlo = (kq & 1) ? z1 : z0;                                    \
            float zhi = (kq & 1) ? z3 : z2;                                    \
            float zl  = ((kq & 2) ? zhi : zlo) + curA;                         \
            float xs  = (kq == 2) ? zl + zl : zl;                              \
            float sg  = sigmoid_f(xs);                                         \
            float av  = (kq == 2) ? fmaf(2.f, sg, -1.f) : sg;                  \
            gbuf[0][ucol * 4 + kq] = av;                                       \
        }                                                                      \
        /* --- row B: 4 gate chains (16 MFMA) --- */                           \
        f32x4 accB[4];                                                         \
        _Pragma("unroll")                                                      \
        for (int g = 0; g < 4; ++g) {                                          \
            f32x4 a = __builtin_amdgcn_mfma_f32_16x16x32_f16(afB[0], bf[0][g], cz, 0, 0, 0); \
            a = __builtin_amdgcn_mfma_f32_16x16x32_f16(afB[1], bf[1][g], a, 0, 0, 0); \
            a = __builtin_amdgcn_mfma_f32_16x16x32_f16(afB[2], bf[2][g], a, 0, 0, 0); \
            a = __builtin_amdgcn_mfma_f32_16x16x32_f16(afB[3], bf[3][g], a, 0, 0, 0); \
            accB[g] = a;                                                       \
        }                                                                      \
        /* --- row A: state update (gbuf seg is wave-private, in-order) --- */ \
        {                                                                      \
            float4 g4 = *(const float4*)&gbuf[0][ucol * 4];                    \
            c0  = fmaf(g4.y, c0, g4.x * g4.z);                                 \
            hv0 = g4.w * tanh_f(c0);                                           \
            if (kq == 0) hbuf[0][(PAR) ^ 1][ucol] = (_Float16)hv0;             \
        }                                                                      \
        /* --- row B: activation + state update --- */                         \
        {                                                                      \
            float z0 = accB[0][0], z1 = accB[1][0], z2 = accB[2][0], z3 = accB[3][0]; \
            float zlo = (kq & 1) ? z1 : z0;                                    \
            float zhi = (kq & 1) ? z3 : z2;                                    \
            float zl  = ((kq & 2) ? zhi : zlo) + curB;                         \
            float xs  = (kq == 2) ? zl + zl : zl;                              \
            float sg  = sigmoid_f(xs);                                         \
            float av  = (kq == 2) ? fmaf(2.f, sg, -1.f) : sg;                  \
            gbuf[1][ucol * 4 + kq] = av;                                       \
            float4 g4 = *(const float4*)&gbuf[1][ucol * 4];                    \
            c1  = fmaf(g4.y, c1, g4.x * g4.z);                                 \
            hv1 = g4.w * tanh_f(c1);                                           \
            if (kq == 1) hbuf[1][(PAR) ^ 1][ucol] = (_Float16)hv1;             \
        }                                                                      \
        asm volatile("s_waitcnt lgkmcnt(0)" ::: "memory");                     \
        __builtin_amdgcn_s_barrier();                                          \
    }

    for (int t = 0; t < TT; t += 2) {
        LSTM_STEP(0, pA0, pB0)
        LSTM_STEP(1, pA1, pB1)
    }
#undef LSTM_STEP

    // --- dense sigmoid head: out[rb+r] = sigmoid(h_r @ w + b) ---
    float v0 = (kq == 0) ? hv0 * dense_w[ucol] : 0.f;
    float v1 = (kq == 0) ? hv1 * dense_w[ucol] : 0.f;
#pragma unroll
    for (int off = 32; off > 0; off >>= 1) {
        v0 += __shfl_xor(v0, off, 64);
        v1 += __shfl_xor(v1, off, 64);
    }
    if (l == 0) { red[0][w] = v0; red[1][w] = v1; }
    __syncthreads();
    if (tid < ROWS) {
        float s = dense_b[0];
#pragma unroll
        for (int i = 0; i < 8; ++i) s += red[tid][i];
        out[rb + tid] = sigmoid_f(s);
    }
}

extern "C" void kernel_launch(void* const* d_in, const int* in_sizes, int n_in,
                              void* d_out, int out_size, void* d_ws, size_t ws_size,
                              hipStream_t stream) {
    const int*   tokens = (const int*)  d_in[0];
    const float* emb    = (const float*)d_in[1];
    const float* wk     = (const float*)d_in[2];
    const float* rk     = (const float*)d_in[3];
    const float* bias   = (const float*)d_in[4];
    const float* dw     = (const float*)d_in[5];
    const float* db     = (const float*)d_in[6];
    float* out = (float*)d_out;
    float* P2  = (float*)d_ws;     // 20000*512*4 = 40.96 MB scratch

    proj_kernel<<<VV / 16, 512, 0, stream>>>(emb, wk, bias, P2);
    lstm_kernel<<<BB / ROWS, 512, 0, stream>>>(tokens, rk, P2, dw, db, out);
}

// Round 9
// 334.010 us; speedup vs baseline: 1.4897x; 1.4897x over previous
//
#include <hip/hip_runtime.h>
#include <hip/hip_bf16.h>

// Problem constants: B,T,V,E,U = 256,512,20000,128,128
#define BB 256
#define TT 512
#define VV 20000
#define EE 128
#define UU 128
#define G4 512   // 4*U gate width

typedef _Float16 half2v __attribute__((ext_vector_type(2)));

__device__ __forceinline__ float sigmoid_f(float x) {
    float e = __expf(-x);
    return __builtin_amdgcn_rcpf(1.0f + e);
}
__device__ __forceinline__ float tanh_f(float x) {
    float e = __expf(2.0f * x);
    return 1.0f - 2.0f * __builtin_amdgcn_rcpf(e + 1.0f);
}

// v_dot2_f32_f16: 2 f16 MACs with f32 accumulate, full VALU rate.
__device__ __forceinline__ float dot2f(half2v a, half2v b, float c) {
    return __builtin_amdgcn_fdot2(a, b, c, false);
}

// quad_perm DPP exchanges (VALU, no LDS pipe, quads = lanes 4u..4u+3)
__device__ __forceinline__ float dpp_q(float v, int pat) {
    switch (pat) {  // compile-time pat via unrolled callers
        case 0xB1: return __int_as_float(__builtin_amdgcn_mov_dpp(__float_as_int(v), 0xB1, 0xF, 0xF, true));
        case 0x4E: return __int_as_float(__builtin_amdgcn_mov_dpp(__float_as_int(v), 0x4E, 0xF, 0xF, true));
        case 0x00: return __int_as_float(__builtin_amdgcn_mov_dpp(__float_as_int(v), 0x00, 0xF, 0xF, true));
        case 0x55: return __int_as_float(__builtin_amdgcn_mov_dpp(__float_as_int(v), 0x55, 0xF, 0xF, true));
        case 0xAA: return __int_as_float(__builtin_amdgcn_mov_dpp(__float_as_int(v), 0xAA, 0xF, 0xF, true));
        default:   return __int_as_float(__builtin_amdgcn_mov_dpp(__float_as_int(v), 0xFF, 0xF, 0xF, true));
    }
}

// ---------------------------------------------------------------------------
// Phase 1: projected-token table in GATE-MINOR layout:
//   P2[v][u][g] = sum_e emb[v][e]*K[e][g*128+u] + bias[g*128+u]
// ---------------------------------------------------------------------------
__global__ __launch_bounds__(512, 2) void proj_kernel(
    const float* __restrict__ emb, const float* __restrict__ wk,
    const float* __restrict__ bias, float* __restrict__ P2) {
    const int tid = threadIdx.x;
    const int g   = tid & 3;
    const int u   = tid >> 2;
    const int col = g * 128 + u;
    const int v0  = blockIdx.x * 16;

    __shared__ float elds[16 * EE];
    ((float4*)elds)[tid] = ((const float4*)(emb + (size_t)v0 * EE))[tid];
    __syncthreads();

    float bcol = bias[col];
    float acc[16];
#pragma unroll
    for (int r = 0; r < 16; ++r) acc[r] = bcol;

    const float4* elds4 = (const float4*)elds;
    for (int e0 = 0; e0 < EE; e0 += 4) {
        float k0 = wk[(e0 + 0) * G4 + col];
        float k1 = wk[(e0 + 1) * G4 + col];
        float k2 = wk[(e0 + 2) * G4 + col];
        float k3 = wk[(e0 + 3) * G4 + col];
#pragma unroll
        for (int r = 0; r < 16; ++r) {
            float4 ev = elds4[r * 32 + (e0 >> 2)];
            acc[r] = fmaf(ev.x, k0, acc[r]);
            acc[r] = fmaf(ev.y, k1, acc[r]);
            acc[r] = fmaf(ev.z, k2, acc[r]);
            acc[r] = fmaf(ev.w, k3, acc[r]);
        }
    }
#pragma unroll
    for (int r = 0; r < 16; ++r)
        P2[(size_t)(v0 + r) * G4 + tid] = acc[r];   // [v][u][g], coalesced
}

// ---------------------------------------------------------------------------
// Phase 2: sequential LSTM on the VECTOR pipe. Rationale: z = h@R is a
// matrix-VECTOR product; MFMA wastes 16x on the M dimension (512 cy/SIMD/step
// pipe floor, measured), while v_dot2_f32_f16 needs only 128 cy/SIMD/step.
// Thread (u=tid>>2, q=tid&3): 32-dim h-slice [32q,32q+32) x 4 gate columns
// of unit u -> 64 f16x2 weight VGPRs, 64 dot2/step, quad DPP butterfly
// completes the 128-dim dots. amdgpu_waves_per_eu(2,2) clamps occupancy so
// the allocator has a hard 256-VGPR budget and no incentive to remat/spill
// the weights (the R2/R3 failure mode). Gate-specialized activation (lane q
// does gate q: 2 trans), acts exchanged by 4 quad-broadcast DPPs, c/h update
// redundant x4 per quad. Depth-2 static P prefetch; lgkmcnt-only barrier.
// ---------------------------------------------------------------------------
__global__ __launch_bounds__(512) __attribute__((amdgpu_waves_per_eu(2, 2)))
void lstm_kernel(
    const int* __restrict__ tokens, const float* __restrict__ rk,
    const float* __restrict__ P2, const float* __restrict__ dense_w,
    const float* __restrict__ dense_b, float* __restrict__ out) {
    const int tid = threadIdx.x;
    const int u   = tid >> 2;       // unit 0..127
    const int q   = tid & 3;        // slice & gate 0..3
    const int b   = blockIdx.x;

    __shared__ __align__(16) _Float16 hh[2][UU];   // double-buffered h (f16)
    __shared__ int   tokLDS[TT + 4];
    __shared__ float red[8];

    // ---- weights: wgt[g][p] = f16x2( rk[32q+2p][g*128+u], rk[32q+2p+1][...] )
    half2v wgt[4][16];
    const float* rkb = rk + (size_t)(32 * q) * G4;
#pragma unroll
    for (int g = 0; g < 4; ++g) {
        const int c = g * 128 + u;
#pragma unroll
        for (int p = 0; p < 16; ++p) {
            half2v hw;
            hw.x = (_Float16)rkb[(2 * p + 0) * G4 + c];
            hw.y = (_Float16)rkb[(2 * p + 1) * G4 + c];
            wgt[g][p] = hw;
        }
    }

    const int* trow = tokens + (size_t)b * TT;
    tokLDS[tid] = trow[tid];
    if (tid < 4) tokLDS[TT + tid] = trow[TT - 1];
    if (tid < UU) hh[0][tid] = (_Float16)0.f;      // h0 = 0

    const int pOff = 4 * u + q;                    // lane's dword in a P2 row
    float c_state = 0.f, hv = 0.f;
    float pf0 = P2[(size_t)trow[0] * G4 + pOff];
    float pf1 = P2[(size_t)trow[1] * G4 + pOff];
    __syncthreads();

#define LSTEP(PAR, PF)                                                        \
    {                                                                         \
        int vtok = tokLDS[t + (PAR) + 2];                                     \
        float pcur = (PF);                        /* waits vmcnt: 2-step-old */\
        (PF) = P2[(size_t)vtok * G4 + pOff];      /* in flight ~2 steps */    \
        const int4* hrow = (const int4*)&hh[PAR][32 * q];                     \
        int4 hA = hrow[0], hB = hrow[1], hC = hrow[2], hD = hrow[3];          \
        half2v h2[16];                                                        \
        h2[0]  = __builtin_bit_cast(half2v, hA.x);                            \
        h2[1]  = __builtin_bit_cast(half2v, hA.y);                            \
        h2[2]  = __builtin_bit_cast(half2v, hA.z);                            \
        h2[3]  = __builtin_bit_cast(half2v, hA.w);                            \
        h2[4]  = __builtin_bit_cast(half2v, hB.x);                            \
        h2[5]  = __builtin_bit_cast(half2v, hB.y);                            \
        h2[6]  = __builtin_bit_cast(half2v, hB.z);                            \
        h2[7]  = __builtin_bit_cast(half2v, hB.w);                            \
        h2[8]  = __builtin_bit_cast(half2v, hC.x);                            \
        h2[9]  = __builtin_bit_cast(half2v, hC.y);                            \
        h2[10] = __builtin_bit_cast(half2v, hC.z);                            \
        h2[11] = __builtin_bit_cast(half2v, hC.w);                            \
        h2[12] = __builtin_bit_cast(half2v, hD.x);                            \
        h2[13] = __builtin_bit_cast(half2v, hD.y);                            \
        h2[14] = __builtin_bit_cast(half2v, hD.z);                            \
        h2[15] = __builtin_bit_cast(half2v, hD.w);                            \
        /* 8 independent dot chains; P injected once per gate (lane q==g) */  \
        float acc0[4], acc1[4];                                               \
        _Pragma("unroll")                                                     \
        for (int g = 0; g < 4; ++g) {                                         \
            acc0[g] = (q == g) ? pcur : 0.f;                                  \
            acc1[g] = 0.f;                                                    \
        }                                                                     \
        _Pragma("unroll")                                                     \
        for (int p = 0; p < 16; p += 2) {                                     \
            _Pragma("unroll")                                                 \
            for (int g = 0; g < 4; ++g) {                                     \
                acc0[g] = dot2f(h2[p],     wgt[g][p],     acc0[g]);           \
                acc1[g] = dot2f(h2[p + 1], wgt[g][p + 1], acc1[g]);           \
            }                                                                 \
        }                                                                     \
        /* quad butterfly: all 4 lanes get full z[g] (incl. its P) */         \
        float z0, z1, z2, z3;                                                 \
        {                                                                     \
            float s;                                                          \
            s = acc0[0] + acc1[0]; s += dpp_q(s, 0xB1); s += dpp_q(s, 0x4E); z0 = s; \
            s = acc0[1] + acc1[1]; s += dpp_q(s, 0xB1); s += dpp_q(s, 0x4E); z1 = s; \
            s = acc0[2] + acc1[2]; s += dpp_q(s, 0xB1); s += dpp_q(s, 0x4E); z2 = s; \
            s = acc0[3] + acc1[3]; s += dpp_q(s, 0xB1); s += dpp_q(s, 0x4E); z3 = s; \
        }                                                                     \
        /* lane q activates gate q only (2 trans) */                          \
        float zlo = (q & 1) ? z1 : z0;                                        \
        float zhi = (q & 1) ? z3 : z2;                                        \
        float zq  = (q & 2) ? zhi : zlo;                                      \
        float xs  = (q == 2) ? zq + zq : zq;                                  \
        float sg  = sigmoid_f(xs);                                            \
        float av  = (q == 2) ? fmaf(2.f, sg, -1.f) : sg;                      \
        /* collect i,f,g,o via quad broadcasts */                             \
        float ai = dpp_q(av, 0x00);                                           \
        float af_ = dpp_q(av, 0x55);                                          \
        float ag = dpp_q(av, 0xAA);                                           \
        float ao = dpp_q(av, 0xFF);                                           \
        c_state = fmaf(af_, c_state, ai * ag);                                \
        hv      = ao * tanh_f(c_state);                                       \
        if (q == 0) hh[(PAR) ^ 1][u] = (_Float16)hv;                          \
        asm volatile("s_waitcnt lgkmcnt(0)" ::: "memory");                    \
        __builtin_amdgcn_s_barrier();                                         \
    }

    for (int t = 0; t < TT; t += 2) {
        LSTEP(0, pf0)
        LSTEP(1, pf1)
    }
#undef LSTEP

    // --- dense sigmoid head: out[b] = sigmoid(h @ w + b) ---
    float val = (q == 0) ? hv * dense_w[u] : 0.f;
#pragma unroll
    for (int off = 32; off > 0; off >>= 1) val += __shfl_xor(val, off, 64);
    if ((tid & 63) == 0) red[tid >> 6] = val;
    __syncthreads();
    if (tid == 0) {
        float s = dense_b[0];
#pragma unroll
        for (int i = 0; i < 8; ++i) s += red[i];
        out[b] = sigmoid_f(s);
    }
}

extern "C" void kernel_launch(void* const* d_in, const int* in_sizes, int n_in,
                              void* d_out, int out_size, void* d_ws, size_t ws_size,
                              hipStream_t stream) {
    const int*   tokens = (const int*)  d_in[0];
    const float* emb    = (const float*)d_in[1];
    const float* wk     = (const float*)d_in[2];
    const float* rk     = (const float*)d_in[3];
    const float* bias   = (const float*)d_in[4];
    const float* dw     = (const float*)d_in[5];
    const float* db     = (const float*)d_in[6];
    float* out = (float*)d_out;
    float* P2  = (float*)d_ws;     // 20000*512*4 = 40.96 MB scratch

    proj_kernel<<<VV / 16, 512, 0, stream>>>(emb, wk, bias, P2);
    lstm_kernel<<<BB, 512, 0, stream>>>(tokens, rk, P2, dw, db, out);
}